// Round 21
// baseline (250.261 us; speedup 1.0000x reference)
//
#include <hip/hip_runtime.h>
#include <math.h>

// PixelQueryNet v21 = v18 ring structure + wave-per-cell remap (LDS halved).
// R20 accounting: the kernel was LDS-INSTRUCTION-bound: 24 groups x 256
// ds_read_b128 per block -> 49k reads/CU x 12cy = 590k cy = the 246us wall.
// Old mapping wasted 8x on A-reads (every wave read the same A data).
// New mapping: wave = one cell j; lanes = 8pg x 8cob. A-read broadcasts to
// all 8 cob within the wave; W-read serves all 8 cob (2-way alias = free).
// Per group: 4 waves x 8ci x 4 reads = 128 insts (was 256).
//
// A layout: word = ci*128 + j*32 + ((pg ^ ((ci>>3)&7))*4) + k, +AHI for k4-7.
//   reads: 8 contiguous distinct quads (conflict-free); writes (ci=cob*8+col,
//   key=cob): quad = (pg^cob) -> conflict-free. 64 KB.
// W tiles: [q(4)][j(4)][cl(2)*64+co]; read addr q*512+j*128+cl*64+cob*8
//   (2-way bank alias, free); publish lane-consecutive (conflict-free).
// Ring WB[2][2048] (16 KB), one barrier per group, single gather pair,
// 4-sibling XCD swizzle (FETCH ideal), LDS 80 KB -> 2 blocks/CU.

static constexpr int PLANE = 4096;
static constexpr int NPAR  = 12995;
static constexpr int AHI   = 8192;  // word offset of k4..7 plane

__device__ __forceinline__ float leaky(float v) { return fmaxf(v, 0.01f * v); }

// PE x-features, compile-time: cos/sin(2*pi*k/8), k = dx.
__device__ __forceinline__ constexpr float cx(int k) {
  constexpr float R = 0.70710678118654752f;
  const float t[8] = {1.f, R, 0.f, -R, -1.f, -R, 0.f, R};
  return t[k];
}
__device__ __forceinline__ constexpr float sx(int k) {
  constexpr float R = 0.70710678118654752f;
  const float t[8] = {0.f, R, 1.f, R, 0.f, -R, -1.f, -R};
  return t[k];
}

__global__ __launch_bounds__(256, 1) void pqn(const float* __restrict__ lr,
                                              float* __restrict__ out) {
  __shared__ alignas(16) float A[2 * AHI];     // 65536 B activations (fp32)
  __shared__ alignas(16) float WB[2][2048];    // 16384 B ring: 2 halves x 4 tiles

  const int tid = threadIdx.x;
  const int pg  = tid & 7;             // pixel row (dy), per-lane
  const int cob = (tid >> 3) & 7;      // co block, per-lane
  const int j   = tid >> 6;            // cell within j-quad = WAVE id

  // ---- swizzle: 4 siblings (same XCD) cover one 64B weight line
  const int n  = blockIdx.x;
  const int e2 = (n >> 3) & 3;
  const int P  = (n & 7) | ((n >> 5) << 3);   // 0..511
  const int jg = ((P & 3) << 2) | e2;         // 0..15
  const int i  = (P >> 2) & 63;
  const int b  = (P >> 8) & 1;

  const float* __restrict__ wb =
      lr + (size_t)b * NPAR * PLANE + (size_t)(i * 64 + jg * 4);
  const float* __restrict__ pt = wb + j;      // per-thread channel base

  float fyc, fys;
  sincosf(0.78539816339744830962f * pg, &fys, &fyc);

  const int jrow = j * 32;             // wave-uniform A base
  const int awr  = jrow + ((pg ^ cob) * 4);   // A write/epilogue offset
  const int wrd  = j * 128 + cob * 8;  // W read base (+ q*512 + cl*64)
  // publish index: channel c=tid -> q=tid>>7, cl=(tid>>6)&1, co=tid&63
  const int pq0  = (tid >> 7) * 512 + ((tid >> 6) & 1) * 64 + (tid & 63);

  auto gaddr = [&](int g) -> size_t {  // first channel of group g's weights
    return 384 + (size_t)(g >> 3) * 4160 + (size_t)(g & 7) * 512;
  };

  float4 paA, paB;                     // single staging pair (1-group flight)
  {
    const size_t cb = gaddr(0);
    paA = *(const float4*)(wb + (cb + tid) * PLANE);
    paB = *(const float4*)(wb + (cb + 256 + tid) * PLANE);
  }
  float l0b[8], l0w[32], bb[8];
#pragma unroll
  for (int m = 0; m < 8; ++m) l0b[m] = pt[(size_t)(cob * 8 + m) * PLANE];
#pragma unroll
  for (int f = 0; f < 4; ++f)
#pragma unroll
    for (int m = 0; m < 8; ++m)
      l0w[f * 8 + m] = pt[(size_t)(64 + f * 64 + cob * 8 + m) * PLANE];
#pragma unroll
  for (int m = 0; m < 8; ++m) bb[m] = pt[(size_t)(320 + cob * 8 + m) * PLANE];

  // ---- L0 compute -> A
#pragma unroll
  for (int col = 0; col < 8; ++col) {
    float t[8];
#pragma unroll
    for (int k = 0; k < 8; ++k) {
      float v = l0b[col];
      v = fmaf(cx(k), l0w[col], v);
      v = fmaf(sx(k), l0w[8 + col], v);
      v = fmaf(fyc,  l0w[16 + col], v);
      v = fmaf(fys,  l0w[24 + col], v);
      t[k] = leaky(v);
    }
    float4 v0, v1;
    v0.x = t[0]; v0.y = t[1]; v0.z = t[2]; v0.w = t[3];
    v1.x = t[4]; v1.y = t[5]; v1.z = t[6]; v1.w = t[7];
    *(float4*)&A[(cob * 8 + col) * 128 + awr]       = v0;
    *(float4*)&A[(cob * 8 + col) * 128 + awr + AHI] = v1;
  }
  // publish group 0 -> half 0; refill Pa <- g1
#pragma unroll
  for (int jj = 0; jj < 4; ++jj) {
    WB[0][pq0 + jj * 128]        = ((const float*)&paA)[jj];
    WB[0][pq0 + 1024 + jj * 128] = ((const float*)&paB)[jj];
  }
  {
    const size_t cb = gaddr(1);
    paA = *(const float4*)(wb + (cb + tid) * PLANE);
    paB = *(const float4*)(wb + (cb + 256 + tid) * PLANE);
  }
  asm volatile("s_waitcnt lgkmcnt(0)" ::: "memory");
  __builtin_amdgcn_s_barrier();
  __builtin_amdgcn_sched_barrier(0);

  float y[64];
#pragma unroll
  for (int m = 0; m < 64; ++m) y[m] = 0.f;

  // one full group: publish g+1 -> other half, refill Pa <- g+2, compute g
  auto group = [&](int g, int h) {     // h = g&1 (literal at call sites)
    if (g + 1 < 24) {                  // publish g+1 from Pa
      float* WD = WB[h ^ 1];
#pragma unroll
      for (int jj = 0; jj < 4; ++jj) {
        WD[pq0 + jj * 128]        = ((const float*)&paA)[jj];
        WD[pq0 + 1024 + jj * 128] = ((const float*)&paB)[jj];
      }
    }
    if (g + 2 < 24) {                  // refill Pa <- g+2 (1-group flight)
      const size_t cb = gaddr(g + 2);
      paA = *(const float4*)(wb + (cb + tid) * PLANE);
      paB = *(const float4*)(wb + (cb + 256 + tid) * PLANE);
    }
    const float* WH = WB[h];
    const int r0 = (g & 7) * 8;
    const int aoff = jrow + ((pg ^ (g & 7)) * 4);
#pragma unroll
    for (int t = 0; t < 8; ++t) {
      const int ci = r0 + t;
      const int q = t >> 1, cl = t & 1;
      const float4 a0 = *(const float4*)&A[ci * 128 + aoff];
      const float4 a1 = *(const float4*)&A[ci * 128 + aoff + AHI];
      const float4 w0 = *(const float4*)&WH[q * 512 + wrd + cl * 64];
      const float4 w1 = *(const float4*)&WH[q * 512 + wrd + cl * 64 + 4];
      const float av[8] = {a0.x, a0.y, a0.z, a0.w, a1.x, a1.y, a1.z, a1.w};
      const float wv[8] = {w0.x, w0.y, w0.z, w0.w, w1.x, w1.y, w1.z, w1.w};
#pragma unroll
      for (int col = 0; col < 8; ++col)
#pragma unroll
        for (int k = 0; k < 8; ++k)
          y[col * 8 + k] = fmaf(av[k], wv[col], y[col * 8 + k]);
    }
    asm volatile("s_waitcnt lgkmcnt(0)" ::: "memory");
    __builtin_amdgcn_s_barrier();
    __builtin_amdgcn_sched_barrier(0);
  };
  auto flush = [&](int l) {            // layer end: bias + leaky -> A
#pragma unroll
    for (int col = 0; col < 8; ++col) {
      float4 v0, v1;
      v0.x = leaky(y[col * 8 + 0] + bb[col]);
      v0.y = leaky(y[col * 8 + 1] + bb[col]);
      v0.z = leaky(y[col * 8 + 2] + bb[col]);
      v0.w = leaky(y[col * 8 + 3] + bb[col]);
      v1.x = leaky(y[col * 8 + 4] + bb[col]);
      v1.y = leaky(y[col * 8 + 5] + bb[col]);
      v1.z = leaky(y[col * 8 + 6] + bb[col]);
      v1.w = leaky(y[col * 8 + 7] + bb[col]);
      *(float4*)&A[(cob * 8 + col) * 128 + awr]       = v0;
      *(float4*)&A[(cob * 8 + col) * 128 + awr + AHI] = v1;
    }
#pragma unroll
    for (int m = 0; m < 64; ++m) y[m] = 0.f;
    if (l < 2) {
#pragma unroll
      for (int m = 0; m < 8; ++m)
        bb[m] = pt[(size_t)(320 + (l + 1) * 4160 + cob * 8 + m) * PLANE];
    }
  };

  // ---- 12 super-iterations of 2 groups; ring half STATIC per position
#pragma unroll 1
  for (int u = 0; u < 12; ++u) {
    const int g0 = u * 2;
    group(g0, 0);
    const int g1 = g0 + 1;
    group(g1, 1);
    if ((g1 & 7) == 7) {               // layer end: flush + extra barrier
      flush(g1 >> 3);
      asm volatile("s_waitcnt lgkmcnt(0)" ::: "memory");
      __builtin_amdgcn_s_barrier();
      __builtin_amdgcn_sched_barrier(0);
    }
  }

  // ---- epilogue: L4 (64 -> 3) + tanh
  float po[24];
#pragma unroll
  for (int m = 0; m < 24; ++m) po[m] = 0.f;
#pragma unroll
  for (int cl = 0; cl < 8; ++cl) {
    const int ci = cob * 8 + cl;
    const float4 a0 = *(const float4*)&A[ci * 128 + awr];
    const float4 a1 = *(const float4*)&A[ci * 128 + awr + AHI];
#pragma unroll
    for (int o = 0; o < 3; ++o) {
      const float w = pt[(size_t)(12803 + ci * 3 + o) * PLANE];
      po[o * 8 + 0] = fmaf(a0.x, w, po[o * 8 + 0]);
      po[o * 8 + 1] = fmaf(a0.y, w, po[o * 8 + 1]);
      po[o * 8 + 2] = fmaf(a0.z, w, po[o * 8 + 2]);
      po[o * 8 + 3] = fmaf(a0.w, w, po[o * 8 + 3]);
      po[o * 8 + 4] = fmaf(a1.x, w, po[o * 8 + 4]);
      po[o * 8 + 5] = fmaf(a1.y, w, po[o * 8 + 5]);
      po[o * 8 + 6] = fmaf(a1.z, w, po[o * 8 + 6]);
      po[o * 8 + 7] = fmaf(a1.w, w, po[o * 8 + 7]);
    }
  }
  asm volatile("s_waitcnt lgkmcnt(0)" ::: "memory");
  __builtin_amdgcn_s_barrier();        // all A reads done -> reuse A
  float* R = A;
#pragma unroll
  for (int m = 0; m < 24; m += 4)
    *(float4*)&R[tid * 28 + m] = *(float4*)&po[m];
  asm volatile("s_waitcnt lgkmcnt(0)" ::: "memory");
  __builtin_amdgcn_s_barrier();
  __builtin_amdgcn_sched_barrier(0);

  if (cob == 0) {                      // 32 threads: one (j, pg) each
#pragma unroll
    for (int o = 0; o < 3; ++o) {
      const float bias = pt[(size_t)(12800 + o) * PLANE];
      float s[8];
#pragma unroll
      for (int k = 0; k < 8; ++k) s[k] = bias;
#pragma unroll
      for (int cb = 0; cb < 8; ++cb) {   // partial of (pg, cb, j) at tid+cb*8
#pragma unroll
        for (int k = 0; k < 8; ++k)
          s[k] += R[(tid + cb * 8) * 28 + o * 8 + k];
      }
      float4 v0, v1;
      v0.x = tanhf(s[0]); v0.y = tanhf(s[1]); v0.z = tanhf(s[2]); v0.w = tanhf(s[3]);
      v1.x = tanhf(s[4]); v1.y = tanhf(s[5]); v1.z = tanhf(s[6]); v1.w = tanhf(s[7]);
      float* op = out + (size_t)b * 786432 + (size_t)o * 262144 +
                  (size_t)(i * 8 + pg) * 512 + (size_t)((jg * 4 + j) * 8);
      *(float4*)op = v0;
      *(float4*)(op + 4) = v1;
    }
  }
}

extern "C" void kernel_launch(void* const* d_in, const int* in_sizes, int n_in,
                              void* d_out, int out_size, void* d_ws, size_t ws_size,
                              hipStream_t stream) {
  (void)in_sizes; (void)n_in; (void)d_ws; (void)ws_size; (void)out_size;
  const float* lr = (const float*)d_in[1];  // d_in[0] = highres (unused by the math)
  float* out = (float*)d_out;
  hipLaunchKernelGGL(pqn, dim3(2048), dim3(256), 0, stream, lr, out);
}